// Round 1
// baseline (1045.643 us; speedup 1.0000x reference)
//
#include <hip/hip_runtime.h>
#include <cstdint>

#define HW 4096
#define NC 256
#define CI 128
#define NB 16
#define MP 1024

// out[c][r] = in[r][c]
__global__ void k_transpose(const float* __restrict__ in, float* __restrict__ out, int R, int CC) {
    int t = blockIdx.x * 256 + threadIdx.x;
    if (t < R * CC) {
        int r = t / CC, c = t % CC;
        out[c * R + r] = in[t];
    }
}

// 1x1 conv: in [B][256][4096], wT [256][128], bias[128] -> out [B][128][4096]
__global__ __launch_bounds__(256) void k_conv(const float* __restrict__ in,
        const float* __restrict__ wT, const float* __restrict__ bias,
        float* __restrict__ out) {
    __shared__ float xs[NC][64];   // 64KB
    int b = blockIdx.x >> 6;
    int nbase = (blockIdx.x & 63) << 6;
    int t = threadIdx.x;
    const float* inb = in + ((size_t)b * NC) * HW + nbase;
    {
        int q = t & 3, c0 = t >> 2;
        #pragma unroll
        for (int k = 0; k < 4; k++) {
            int c = c0 + (k << 6);
            const float4* src = (const float4*)(inb + (size_t)c * HW + (q << 4));
            float4* dst = (float4*)&xs[c][q << 4];
            #pragma unroll
            for (int j = 0; j < 4; j++) dst[j] = src[j];
        }
    }
    __syncthreads();
    int to = t >> 4, tn = t & 15;
    int obase = to << 3, nloc = tn << 2;
    float4 acc[8];
    #pragma unroll
    for (int oi = 0; oi < 8; oi++) acc[oi] = make_float4(0.f, 0.f, 0.f, 0.f);
    #pragma unroll 4
    for (int c = 0; c < NC; c++) {
        float4 xv = *(float4*)&xs[c][nloc];
        float4 w0 = *(const float4*)&wT[c * CI + obase];
        float4 w1 = *(const float4*)&wT[c * CI + obase + 4];
        float wv[8] = {w0.x, w0.y, w0.z, w0.w, w1.x, w1.y, w1.z, w1.w};
        #pragma unroll
        for (int oi = 0; oi < 8; oi++) {
            acc[oi].x += wv[oi] * xv.x; acc[oi].y += wv[oi] * xv.y;
            acc[oi].z += wv[oi] * xv.z; acc[oi].w += wv[oi] * xv.w;
        }
    }
    #pragma unroll
    for (int oi = 0; oi < 8; oi++) {
        int o = obase + oi;
        float bv = bias[o];
        float4 r = acc[oi];
        r.x += bv; r.y += bv; r.z += bv; r.w += bv;
        *(float4*)&out[((size_t)b * CI + o) * HW + nbase + nloc] = r;
    }
}

// 2x2 maxpool: full [B][128][4096] -> pool [B][128][1024]
__global__ void k_pool(const float* __restrict__ full, float* __restrict__ pool) {
    int b = blockIdx.x >> 7, ci = blockIdx.x & 127;
    const float* src = full + ((size_t)b * CI + ci) * HW;
    float* dst = pool + ((size_t)b * CI + ci) * MP;
    int t = threadIdx.x;
    #pragma unroll
    for (int k = 0; k < 4; k++) {
        int m = t + (k << 8);
        int ph = m >> 5, pw = m & 31;
        int base = (ph << 7) + (pw << 1);
        float a = src[base], b2 = src[base + 1], c2 = src[base + 64], d2 = src[base + 65];
        dst[m] = fmaxf(fmaxf(a, b2), fmaxf(c2, d2));
    }
}

// attention: theta [B][128][4096], phi [B][128][1024], g [B][128][1024] -> z [B][4096][128]
__global__ __launch_bounds__(256) void k_attn(const float* __restrict__ theta,
        const float* __restrict__ phi, const float* __restrict__ g,
        float* __restrict__ z) {
    __shared__ float ts[16][CI];     // 8KB
    __shared__ float fs[16][MP];     // 64KB
    __shared__ float rsum[16];
    int b = blockIdx.x >> 8;
    int nbase = (blockIdx.x & 255) << 4;
    int t = threadIdx.x;
    {
        int c = t & 127, gg = t >> 7;
        #pragma unroll
        for (int j = 0; j < 8; j++) {
            int nl = (gg << 3) + j;
            ts[nl][c] = theta[((size_t)b * CI + c) * HW + nbase + nl];
        }
    }
    __syncthreads();
    const float* phib = phi + (size_t)b * CI * MP;
    {
        int m4 = t << 2;
        float4 f4[16];
        #pragma unroll
        for (int n = 0; n < 16; n++) f4[n] = make_float4(0.f, 0.f, 0.f, 0.f);
        for (int c = 0; c < CI; c += 4) {
            float4 p0 = *(const float4*)&phib[(size_t)(c + 0) * MP + m4];
            float4 p1 = *(const float4*)&phib[(size_t)(c + 1) * MP + m4];
            float4 p2 = *(const float4*)&phib[(size_t)(c + 2) * MP + m4];
            float4 p3 = *(const float4*)&phib[(size_t)(c + 3) * MP + m4];
            #pragma unroll
            for (int n = 0; n < 16; n++) {
                float4 tv = *(float4*)&ts[n][c];
                f4[n].x += tv.x * p0.x + tv.y * p1.x + tv.z * p2.x + tv.w * p3.x;
                f4[n].y += tv.x * p0.y + tv.y * p1.y + tv.z * p2.y + tv.w * p3.y;
                f4[n].z += tv.x * p0.z + tv.y * p1.z + tv.z * p2.z + tv.w * p3.z;
                f4[n].w += tv.x * p0.w + tv.y * p1.w + tv.z * p2.w + tv.w * p3.w;
            }
        }
        #pragma unroll
        for (int n = 0; n < 16; n++) *(float4*)&fs[n][m4] = f4[n];
    }
    __syncthreads();
    {
        int wave = t >> 6, lane = t & 63;
        #pragma unroll
        for (int r = 0; r < 4; r++) {
            int n = (wave << 2) + r;
            float v[16];
            float mx = -3.4e38f;
            #pragma unroll
            for (int k = 0; k < 16; k++) { v[k] = fs[n][lane + (k << 6)]; mx = fmaxf(mx, v[k]); }
            #pragma unroll
            for (int d = 32; d > 0; d >>= 1) mx = fmaxf(mx, __shfl_xor(mx, d, 64));
            float sum = 0.f;
            #pragma unroll
            for (int k = 0; k < 16; k++) {
                float e = __expf(v[k] - mx);
                sum += e;
                fs[n][lane + (k << 6)] = e;
            }
            #pragma unroll
            for (int d = 32; d > 0; d >>= 1) sum += __shfl_xor(sum, d, 64);
            if (lane == 0) rsum[n] = 1.f / sum;
        }
    }
    __syncthreads();
    const float* gb = g + (size_t)b * CI * MP;
    int cp = t & 63, h = t >> 6;
    int ci0 = cp << 1;
    float2 acc[16];
    #pragma unroll
    for (int n = 0; n < 16; n++) acc[n] = make_float2(0.f, 0.f);
    const float* g0p = gb + (size_t)ci0 * MP + (h << 8);
    const float* g1p = g0p + MP;
    for (int mm = 0; mm < 64; mm++) {
        int m = (h << 8) + (mm << 2);
        float4 g0 = *(const float4*)&g0p[mm << 2];
        float4 g1 = *(const float4*)&g1p[mm << 2];
        #pragma unroll
        for (int n = 0; n < 16; n++) {
            float4 p = *(float4*)&fs[n][m];
            acc[n].x += p.x * g0.x + p.y * g0.y + p.z * g0.z + p.w * g0.w;
            acc[n].y += p.x * g1.x + p.y * g1.y + p.z * g1.z + p.w * g1.w;
        }
    }
    __syncthreads();
    float* part = &fs[0][0];   // reuse as [4][16][128]
    #pragma unroll
    for (int n = 0; n < 16; n++) {
        *(float2*)&part[((h << 4) + n) * CI + ci0] = acc[n];
    }
    __syncthreads();
    {
        int ci = t & 127, nh = t >> 7;
        #pragma unroll
        for (int j = 0; j < 8; j++) {
            int n = (nh << 3) + j;
            float s = part[n * CI + ci] + part[(16 + n) * CI + ci]
                    + part[(32 + n) * CI + ci] + part[(48 + n) * CI + ci];
            z[((size_t)b * HW + nbase + n) * CI + ci] = s * rsum[n];
        }
    }
}

// wz = W z + b: z [B][4096][128], wT2 [128][256] -> out [B][256][4096], per-block BN partials
__global__ __launch_bounds__(256) void k_wz(const float* __restrict__ z,
        const float* __restrict__ wT2, const float* __restrict__ Wb,
        float* __restrict__ out, float* __restrict__ part, float* __restrict__ partq) {
    __shared__ float zs[64][CI];   // 32KB
    int b = blockIdx.x >> 6;
    int nbase = (blockIdx.x & 63) << 6;
    int t = threadIdx.x;
    {
        int nl = t >> 2, q = t & 3;
        const float4* src = (const float4*)&z[((size_t)b * HW + nbase + nl) * CI + (q << 5)];
        float4* dst = (float4*)&zs[nl][q << 5];
        #pragma unroll
        for (int j = 0; j < 8; j++) dst[j] = src[j];
    }
    __syncthreads();
    int nh = t & 7, oh = t >> 3;
    float acc[8][8];
    #pragma unroll
    for (int a = 0; a < 8; a++) {
        #pragma unroll
        for (int o = 0; o < 8; o++) acc[a][o] = 0.f;
    }
    for (int c = 0; c < CI; c += 4) {
        float wv[4][8];
        #pragma unroll
        for (int cj = 0; cj < 4; cj++) {
            float4 wa = *(const float4*)&wT2[(size_t)(c + cj) * NC + (oh << 3)];
            float4 wb2 = *(const float4*)&wT2[(size_t)(c + cj) * NC + (oh << 3) + 4];
            wv[cj][0] = wa.x; wv[cj][1] = wa.y; wv[cj][2] = wa.z; wv[cj][3] = wa.w;
            wv[cj][4] = wb2.x; wv[cj][5] = wb2.y; wv[cj][6] = wb2.z; wv[cj][7] = wb2.w;
        }
        #pragma unroll
        for (int nj = 0; nj < 8; nj++) {
            float4 zv = *(float4*)&zs[(nh << 3) + nj][c];
            #pragma unroll
            for (int oj = 0; oj < 8; oj++) {
                acc[nj][oj] += zv.x * wv[0][oj] + zv.y * wv[1][oj]
                             + zv.z * wv[2][oj] + zv.w * wv[3][oj];
            }
        }
    }
    float bs[8], bq[8];
    #pragma unroll
    for (int oj = 0; oj < 8; oj++) { bs[oj] = 0.f; bq[oj] = 0.f; }
    #pragma unroll
    for (int oj = 0; oj < 8; oj++) {
        int o = (oh << 3) + oj;
        float bv = Wb[o];
        float vals[8];
        #pragma unroll
        for (int nj = 0; nj < 8; nj++) {
            float v = acc[nj][oj] + bv;
            vals[nj] = v;
            bs[oj] += v;
            bq[oj] += v * v;
        }
        float4 s0 = make_float4(vals[0], vals[1], vals[2], vals[3]);
        float4 s1 = make_float4(vals[4], vals[5], vals[6], vals[7]);
        float* dst = &out[((size_t)b * NC + o) * HW + nbase + (nh << 3)];
        *(float4*)dst = s0;
        *(float4*)(dst + 4) = s1;
    }
    __syncthreads();
    float* red = &zs[0][0];   // reuse: 2 x [8][256]
    #pragma unroll
    for (int oj = 0; oj < 8; oj++) {
        red[nh * NC + (oh << 3) + oj] = bs[oj];
        red[2048 + nh * NC + (oh << 3) + oj] = bq[oj];
    }
    __syncthreads();
    {
        float s = 0.f, q = 0.f;
        #pragma unroll
        for (int k = 0; k < 8; k++) { s += red[k * NC + t]; q += red[2048 + k * NC + t]; }
        part[(size_t)blockIdx.x * NC + t] = s;
        partq[(size_t)blockIdx.x * NC + t] = q;
    }
}

// reduce partials -> scale/shift per channel
__global__ __launch_bounds__(256) void k_bnstats(const float* __restrict__ part,
        const float* __restrict__ partq, const float* __restrict__ gamma,
        const float* __restrict__ beta, float* __restrict__ ss) {
    int o = blockIdx.x, t = threadIdx.x;
    float s = 0.f, q = 0.f;
    for (int k = t; k < 1024; k += 256) {
        s += part[(size_t)k * NC + o];
        q += partq[(size_t)k * NC + o];
    }
    #pragma unroll
    for (int d = 32; d > 0; d >>= 1) { s += __shfl_down(s, d, 64); q += __shfl_down(q, d, 64); }
    __shared__ float rs[4], rq[4];
    int wave = t >> 6, lane = t & 63;
    if (lane == 0) { rs[wave] = s; rq[wave] = q; }
    __syncthreads();
    if (t == 0) {
        float S = rs[0] + rs[1] + rs[2] + rs[3];
        float Q = rq[0] + rq[1] + rq[2] + rq[3];
        const float inv = 1.0f / 65536.0f;
        float mean = S * inv;
        float var = Q * inv - mean * mean;
        float sc = gamma[o] * rsqrtf(var + 1e-5f);
        ss[o] = sc;
        ss[NC + o] = beta[o] - mean * sc;
    }
}

// out = wz*scale + shift + x (in place on d_out)
__global__ void k_apply(float* __restrict__ out, const float* __restrict__ x,
        const float* __restrict__ ss) {
    size_t i4 = (size_t)blockIdx.x * 256 + threadIdx.x;
    int o = (int)((i4 >> 10) & 255);
    float sc = ss[o], sh = ss[NC + o];
    float4 w = ((float4*)out)[i4];
    float4 xv = ((const float4*)x)[i4];
    float4 r;
    r.x = w.x * sc + sh + xv.x;
    r.y = w.y * sc + sh + xv.y;
    r.z = w.z * sc + sh + xv.z;
    r.w = w.w * sc + sh + xv.w;
    ((float4*)out)[i4] = r;
}

extern "C" void kernel_launch(void* const* d_in, const int* in_sizes, int n_in,
                              void* d_out, int out_size, void* d_ws, size_t ws_size,
                              hipStream_t stream) {
    const float* x       = (const float*)d_in[0];
    const float* y       = (const float*)d_in[1];
    const float* theta_w = (const float*)d_in[2];
    const float* theta_b = (const float*)d_in[3];
    const float* phi_w   = (const float*)d_in[4];
    const float* phi_b   = (const float*)d_in[5];
    const float* g_w     = (const float*)d_in[6];
    const float* g_b     = (const float*)d_in[7];
    const float* W_w     = (const float*)d_in[8];
    const float* W_b     = (const float*)d_in[9];
    const float* bn_g    = (const float*)d_in[10];
    const float* bn_b    = (const float*)d_in[11];
    float* ws  = (float*)d_ws;
    float* out = (float*)d_out;

    float* wT0     = ws;                     // [256][128]
    float* wT1     = ws + 32768;
    float* wT2g    = ws + 65536;
    float* wTW     = ws + 98304;             // [128][256]
    float* buf     = ws + 131072;            // 8388608: phi_full / g_full, then z
    float* theta_x = buf + 8388608;          // 8388608
    float* phip    = theta_x + 8388608;      // 2097152
    float* gp      = phip + 2097152;         // 2097152
    float* part    = gp + 2097152;           // 262144
    float* partq   = part + 262144;          // 262144
    float* ss      = partq + 262144;         // 512
    float* zbuf    = buf;

    k_transpose<<<128, 256, 0, stream>>>(theta_w, wT0, CI, NC);
    k_transpose<<<128, 256, 0, stream>>>(phi_w,   wT1, CI, NC);
    k_transpose<<<128, 256, 0, stream>>>(g_w,     wT2g, CI, NC);
    k_transpose<<<128, 256, 0, stream>>>(W_w,     wTW, NC, CI);

    k_conv<<<NB * 64, 256, 0, stream>>>(x, wT0, theta_b, theta_x);
    k_conv<<<NB * 64, 256, 0, stream>>>(y, wT1, phi_b, buf);
    k_pool<<<NB * CI, 256, 0, stream>>>(buf, phip);
    k_conv<<<NB * 64, 256, 0, stream>>>(y, wT2g, g_b, buf);
    k_pool<<<NB * CI, 256, 0, stream>>>(buf, gp);

    k_attn<<<NB * 256, 256, 0, stream>>>(theta_x, phip, gp, zbuf);

    k_wz<<<NB * 64, 256, 0, stream>>>(zbuf, wTW, W_b, out, part, partq);
    k_bnstats<<<256, 256, 0, stream>>>(part, partq, bn_g, bn_b, ss);
    k_apply<<<16384, 256, 0, stream>>>(out, x, ss);
}

// Round 2
// 488.789 us; speedup vs baseline: 2.1393x; 2.1393x over previous
//
#include <hip/hip_runtime.h>
#include <cstdint>

#define HW 4096
#define NC 256
#define CI 128
#define NB 16
#define MP 1024

typedef __bf16 bfv8 __attribute__((ext_vector_type(8)));
typedef float f32x16 __attribute__((ext_vector_type(16)));

__device__ __forceinline__ uint32_t bfr(float x) {
    uint32_t u = __float_as_uint(x);
    return (u + 0x7fffu + ((u >> 16) & 1u)) >> 16;
}
__device__ __forceinline__ uint32_t pkbf(float a, float b) {
    return bfr(a) | (bfr(b) << 16);
}
__device__ __forceinline__ float b2f_lo(uint32_t u) { return __uint_as_float(u << 16); }
__device__ __forceinline__ float b2f_hi(uint32_t u) { return __uint_as_float(u & 0xffff0000u); }

// out[c][r] = in[r][c]
__global__ void k_transpose(const float* __restrict__ in, float* __restrict__ out, int R, int CC) {
    int t = blockIdx.x * 256 + threadIdx.x;
    if (t < R * CC) {
        int r = t / CC, c = t % CC;
        out[c * R + r] = in[t];
    }
}

// 1x1 conv: in [B][256][4096], wT [256][128] -> out fp32 [B][128][4096]  (g branch)
__global__ __launch_bounds__(256) void k_conv(const float* __restrict__ in,
        const float* __restrict__ wT, const float* __restrict__ bias,
        float* __restrict__ out) {
    __shared__ float xs[NC][64];
    int b = blockIdx.x >> 6;
    int nbase = (blockIdx.x & 63) << 6;
    int t = threadIdx.x;
    const float* inb = in + ((size_t)b * NC) * HW + nbase;
    {
        int q = t & 3, c0 = t >> 2;
        #pragma unroll
        for (int k = 0; k < 4; k++) {
            int c = c0 + (k << 6);
            const float4* src = (const float4*)(inb + (size_t)c * HW + (q << 4));
            float4* dst = (float4*)&xs[c][q << 4];
            #pragma unroll
            for (int j = 0; j < 4; j++) dst[j] = src[j];
        }
    }
    __syncthreads();
    int to = t >> 4, tn = t & 15;
    int obase = to << 3, nloc = tn << 2;
    float4 acc[8];
    #pragma unroll
    for (int oi = 0; oi < 8; oi++) acc[oi] = make_float4(0.f, 0.f, 0.f, 0.f);
    #pragma unroll 4
    for (int c = 0; c < NC; c++) {
        float4 xv = *(float4*)&xs[c][nloc];
        float4 w0 = *(const float4*)&wT[c * CI + obase];
        float4 w1 = *(const float4*)&wT[c * CI + obase + 4];
        float wv[8] = {w0.x, w0.y, w0.z, w0.w, w1.x, w1.y, w1.z, w1.w};
        #pragma unroll
        for (int oi = 0; oi < 8; oi++) {
            acc[oi].x += wv[oi] * xv.x; acc[oi].y += wv[oi] * xv.y;
            acc[oi].z += wv[oi] * xv.z; acc[oi].w += wv[oi] * xv.w;
        }
    }
    #pragma unroll
    for (int oi = 0; oi < 8; oi++) {
        int o = obase + oi;
        float bv = bias[o];
        float4 r = acc[oi];
        r.x += bv; r.y += bv; r.z += bv; r.w += bv;
        *(float4*)&out[((size_t)b * CI + o) * HW + nbase + nloc] = r;
    }
}

// 1x1 conv, transposed bf16 output: out [B][4096][128] bf16  (theta / phi branches)
__global__ __launch_bounds__(256) void k_conv_t(const float* __restrict__ in,
        const float* __restrict__ wT, const float* __restrict__ bias,
        ushort* __restrict__ out) {
    __shared__ float xs[NC][64];
    int b = blockIdx.x >> 6;
    int nbase = (blockIdx.x & 63) << 6;
    int t = threadIdx.x;
    const float* inb = in + ((size_t)b * NC) * HW + nbase;
    {
        int q = t & 3, c0 = t >> 2;
        #pragma unroll
        for (int k = 0; k < 4; k++) {
            int c = c0 + (k << 6);
            const float4* src = (const float4*)(inb + (size_t)c * HW + (q << 4));
            float4* dst = (float4*)&xs[c][q << 4];
            #pragma unroll
            for (int j = 0; j < 4; j++) dst[j] = src[j];
        }
    }
    __syncthreads();
    int to = t >> 4, tn = t & 15;
    int obase = to << 3, nloc = tn << 2;
    float4 acc[8];
    #pragma unroll
    for (int oi = 0; oi < 8; oi++) acc[oi] = make_float4(0.f, 0.f, 0.f, 0.f);
    #pragma unroll 4
    for (int c = 0; c < NC; c++) {
        float4 xv = *(float4*)&xs[c][nloc];
        float4 w0 = *(const float4*)&wT[c * CI + obase];
        float4 w1 = *(const float4*)&wT[c * CI + obase + 4];
        float wv[8] = {w0.x, w0.y, w0.z, w0.w, w1.x, w1.y, w1.z, w1.w};
        #pragma unroll
        for (int oi = 0; oi < 8; oi++) {
            acc[oi].x += wv[oi] * xv.x; acc[oi].y += wv[oi] * xv.y;
            acc[oi].z += wv[oi] * xv.z; acc[oi].w += wv[oi] * xv.w;
        }
    }
    float bv[8];
    #pragma unroll
    for (int oi = 0; oi < 8; oi++) bv[oi] = bias[obase + oi];
    #pragma unroll
    for (int j = 0; j < 4; j++) {
        float v[8];
        #pragma unroll
        for (int oi = 0; oi < 8; oi++) v[oi] = (&acc[oi].x)[j] + bv[oi];
        uint4 pk4;
        pk4.x = pkbf(v[0], v[1]); pk4.y = pkbf(v[2], v[3]);
        pk4.z = pkbf(v[4], v[5]); pk4.w = pkbf(v[6], v[7]);
        *(uint4*)&out[((size_t)b * HW + nbase + nloc + j) * CI + obase] = pk4;
    }
}

// pool bf16 [B][4096][128] -> bf16 [B][1024][128]  (phi^T path)
__global__ __launch_bounds__(256) void k_pool_t(const ushort* __restrict__ in,
        ushort* __restrict__ out) {
    int b = blockIdx.x >> 2;
    int mbase = (blockIdx.x & 3) << 8;
    int t = threadIdx.x;
    int c2 = t & 63, mg = t >> 6;
    const uint32_t* ib = (const uint32_t*)(in + (size_t)b * HW * CI);
    uint32_t* ob = (uint32_t*)(out + (size_t)b * MP * CI);
    for (int j = 0; j < 64; j++) {
        int m = mbase + (j << 2) + mg;
        int ph = m >> 5, pw = m & 31;
        int n0 = (ph << 7) + (pw << 1);
        uint32_t a0 = ib[(size_t)n0 * 64 + c2];
        uint32_t a1 = ib[(size_t)(n0 + 1) * 64 + c2];
        uint32_t a2 = ib[(size_t)(n0 + 64) * 64 + c2];
        uint32_t a3 = ib[(size_t)(n0 + 65) * 64 + c2];
        float lo = fmaxf(fmaxf(b2f_lo(a0), b2f_lo(a1)), fmaxf(b2f_lo(a2), b2f_lo(a3)));
        float hi = fmaxf(fmaxf(b2f_hi(a0), b2f_hi(a1)), fmaxf(b2f_hi(a2), b2f_hi(a3)));
        ob[(size_t)m * 64 + c2] = (__float_as_uint(lo) >> 16) | (__float_as_uint(hi) & 0xffff0000u);
    }
}

// pool fp32 [B][128][4096] -> bf16 [B][128][1024]  (g path)
__global__ void k_pool_bf(const float* __restrict__ full, ushort* __restrict__ pool) {
    int b = blockIdx.x >> 7, ci = blockIdx.x & 127;
    const float* src = full + ((size_t)b * CI + ci) * HW;
    ushort* dst = pool + ((size_t)b * CI + ci) * MP;
    int t = threadIdx.x;
    #pragma unroll
    for (int k = 0; k < 4; k++) {
        int m = t + (k << 8);
        int ph = m >> 5, pw = m & 31;
        int base = (ph << 7) + (pw << 1);
        float a = src[base], b2 = src[base + 1], c2 = src[base + 64], d2 = src[base + 65];
        float v = fmaxf(fmaxf(a, b2), fmaxf(c2, d2));
        dst[m] = (ushort)bfr(v);
    }
}

// flash attention with MFMA: thetaT [B][4096][128] bf16, phiT [B][1024][128] bf16,
// g [B][128][1024] bf16 -> z [B][4096][128] fp32
__global__ __launch_bounds__(256) void k_attn_mfma(
        const ushort* __restrict__ thetaT, const ushort* __restrict__ phiT,
        const ushort* __restrict__ gmat, float* __restrict__ z) {
    int t = threadIdx.x;
    int wave = t >> 6, lane = t & 63;
    int nq = lane & 31, hi = lane >> 5;
    int b = blockIdx.x >> 5;
    int nblk = blockIdx.x & 31;
    int n0 = (nblk << 7) + (wave << 5);

    // hoisted Q fragments (B-operand): col n = nq, k = kstep*16 + hi*8 + [0..7]
    bfv8 qf[8];
    {
        const ushort* tb = thetaT + ((size_t)b * HW + n0 + nq) * CI + hi * 8;
        #pragma unroll
        for (int s = 0; s < 8; s++) qf[s] = *(const bfv8*)(tb + s * 16);
    }
    f32x16 zacc[4];
    #pragma unroll
    for (int ct = 0; ct < 4; ct++)
        #pragma unroll
        for (int i = 0; i < 16; i++) zacc[ct][i] = 0.f;
    float run_max = -1e30f, run_sum = 0.f;

    const ushort* pb = phiT + ((size_t)b * MP + nq) * CI + hi * 8;
    const ushort* gb = gmat + ((size_t)b * CI + nq) * MP + hi * 8;

    for (int m0 = 0; m0 < MP; m0 += 32) {
        // S^T tile: D[m][n] = sum_c phi[m][c] * theta[n][c]
        f32x16 s;
        #pragma unroll
        for (int i = 0; i < 16; i++) s[i] = 0.f;
        const ushort* pa = pb + (size_t)m0 * CI;
        #pragma unroll
        for (int ks = 0; ks < 8; ks++) {
            bfv8 af = *(const bfv8*)(pa + ks * 16);
            s = __builtin_amdgcn_mfma_f32_32x32x16_bf16(af, qf[ks], s, 0, 0, 0);
        }
        // online softmax over m (lane-local + partner lane^32)
        float mx = s[0];
        #pragma unroll
        for (int i = 1; i < 16; i++) mx = fmaxf(mx, s[i]);
        float gmx = fmaxf(mx, __shfl_xor(mx, 32, 64));
        if (!__all(gmx - run_max <= 8.0f)) {
            float nm = fmaxf(run_max, gmx);
            float sc = __expf(run_max - nm);
            run_sum *= sc;
            #pragma unroll
            for (int ct = 0; ct < 4; ct++)
                #pragma unroll
                for (int i = 0; i < 16; i++) zacc[ct][i] *= sc;
            run_max = nm;
        }
        float p[16];
        #pragma unroll
        for (int i = 0; i < 16; i++) { p[i] = __expf(s[i] - run_max); run_sum += p[i]; }
        // pack P to bf16 B-fragments (k = m), exchange halves with lane^32
        uint32_t w[8], sw[8];
        #pragma unroll
        for (int j = 0; j < 8; j++) w[j] = pkbf(p[2 * j], p[2 * j + 1]);
        #pragma unroll
        for (int j = 0; j < 8; j++) sw[j] = (uint32_t)__shfl_xor((int)w[j], 32, 64);
        bool lo = (hi == 0);
        union PU { uint32_t u[4]; bfv8 v; } p0u, p1u;
        p0u.u[0] = lo ? w[0] : sw[2];
        p0u.u[1] = lo ? w[1] : sw[3];
        p0u.u[2] = lo ? sw[0] : w[2];
        p0u.u[3] = lo ? sw[1] : w[3];
        p1u.u[0] = lo ? w[4] : sw[6];
        p1u.u[1] = lo ? w[5] : sw[7];
        p1u.u[2] = lo ? sw[4] : w[6];
        p1u.u[3] = lo ? sw[5] : w[7];
        // PV: z^T[c][n] += g[c][m-chunk] * P[m-chunk][n]
        #pragma unroll
        for (int ct = 0; ct < 4; ct++) {
            const ushort* ga = gb + ((size_t)ct * 32) * MP + m0;
            bfv8 a0 = *(const bfv8*)ga;
            bfv8 a1 = *(const bfv8*)(ga + 16);
            zacc[ct] = __builtin_amdgcn_mfma_f32_32x32x16_bf16(a0, p0u.v, zacc[ct], 0, 0, 0);
            zacc[ct] = __builtin_amdgcn_mfma_f32_32x32x16_bf16(a1, p1u.v, zacc[ct], 0, 0, 0);
        }
    }
    float tot = run_sum + __shfl_xor(run_sum, 32, 64);
    float rinv = 1.f / tot;
    // write z[n][c]: lane owns row n0+nq; regs give 4 consecutive c per float4
    float* zr = z + ((size_t)b * HW + n0 + nq) * CI;
    #pragma unroll
    for (int ct = 0; ct < 4; ct++) {
        int cb = (ct << 5) + (hi << 2);
        #pragma unroll
        for (int grp = 0; grp < 4; grp++) {
            float4 v;
            v.x = zacc[ct][grp * 4 + 0] * rinv;
            v.y = zacc[ct][grp * 4 + 1] * rinv;
            v.z = zacc[ct][grp * 4 + 2] * rinv;
            v.w = zacc[ct][grp * 4 + 3] * rinv;
            *(float4*)(zr + cb + grp * 8) = v;
        }
    }
}

// wz = W z + b: z [B][4096][128] fp32, wT2 [128][256] -> out [B][256][4096], BN partials
__global__ __launch_bounds__(256) void k_wz(const float* __restrict__ z,
        const float* __restrict__ wT2, const float* __restrict__ Wb,
        float* __restrict__ out, float* __restrict__ part, float* __restrict__ partq) {
    __shared__ float zs[64][CI];
    int b = blockIdx.x >> 6;
    int nbase = (blockIdx.x & 63) << 6;
    int t = threadIdx.x;
    {
        int nl = t >> 2, q = t & 3;
        const float4* src = (const float4*)&z[((size_t)b * HW + nbase + nl) * CI + (q << 5)];
        float4* dst = (float4*)&zs[nl][q << 5];
        #pragma unroll
        for (int j = 0; j < 8; j++) dst[j] = src[j];
    }
    __syncthreads();
    int nh = t & 7, oh = t >> 3;
    float acc[8][8];
    #pragma unroll
    for (int a = 0; a < 8; a++)
        #pragma unroll
        for (int o = 0; o < 8; o++) acc[a][o] = 0.f;
    for (int c = 0; c < CI; c += 4) {
        float wv[4][8];
        #pragma unroll
        for (int cj = 0; cj < 4; cj++) {
            float4 wa = *(const float4*)&wT2[(size_t)(c + cj) * NC + (oh << 3)];
            float4 wb2 = *(const float4*)&wT2[(size_t)(c + cj) * NC + (oh << 3) + 4];
            wv[cj][0] = wa.x; wv[cj][1] = wa.y; wv[cj][2] = wa.z; wv[cj][3] = wa.w;
            wv[cj][4] = wb2.x; wv[cj][5] = wb2.y; wv[cj][6] = wb2.z; wv[cj][7] = wb2.w;
        }
        #pragma unroll
        for (int nj = 0; nj < 8; nj++) {
            float4 zv = *(float4*)&zs[(nh << 3) + nj][c];
            #pragma unroll
            for (int oj = 0; oj < 8; oj++) {
                acc[nj][oj] += zv.x * wv[0][oj] + zv.y * wv[1][oj]
                             + zv.z * wv[2][oj] + zv.w * wv[3][oj];
            }
        }
    }
    float bs[8], bq[8];
    #pragma unroll
    for (int oj = 0; oj < 8; oj++) { bs[oj] = 0.f; bq[oj] = 0.f; }
    #pragma unroll
    for (int oj = 0; oj < 8; oj++) {
        int o = (oh << 3) + oj;
        float bv = Wb[o];
        float vals[8];
        #pragma unroll
        for (int nj = 0; nj < 8; nj++) {
            float v = acc[nj][oj] + bv;
            vals[nj] = v;
            bs[oj] += v;
            bq[oj] += v * v;
        }
        float4 s0 = make_float4(vals[0], vals[1], vals[2], vals[3]);
        float4 s1 = make_float4(vals[4], vals[5], vals[6], vals[7]);
        float* dst = &out[((size_t)b * NC + o) * HW + nbase + (nh << 3)];
        *(float4*)dst = s0;
        *(float4*)(dst + 4) = s1;
    }
    __syncthreads();
    float* red = &zs[0][0];
    #pragma unroll
    for (int oj = 0; oj < 8; oj++) {
        red[nh * NC + (oh << 3) + oj] = bs[oj];
        red[2048 + nh * NC + (oh << 3) + oj] = bq[oj];
    }
    __syncthreads();
    {
        float s = 0.f, q = 0.f;
        #pragma unroll
        for (int k = 0; k < 8; k++) { s += red[k * NC + t]; q += red[2048 + k * NC + t]; }
        part[(size_t)blockIdx.x * NC + t] = s;
        partq[(size_t)blockIdx.x * NC + t] = q;
    }
}

__global__ __launch_bounds__(256) void k_bnstats(const float* __restrict__ part,
        const float* __restrict__ partq, const float* __restrict__ gamma,
        const float* __restrict__ beta, float* __restrict__ ss) {
    int o = blockIdx.x, t = threadIdx.x;
    float s = 0.f, q = 0.f;
    for (int k = t; k < 1024; k += 256) {
        s += part[(size_t)k * NC + o];
        q += partq[(size_t)k * NC + o];
    }
    #pragma unroll
    for (int d = 32; d > 0; d >>= 1) { s += __shfl_down(s, d, 64); q += __shfl_down(q, d, 64); }
    __shared__ float rs[4], rq[4];
    int wave = t >> 6, lane = t & 63;
    if (lane == 0) { rs[wave] = s; rq[wave] = q; }
    __syncthreads();
    if (t == 0) {
        float S = rs[0] + rs[1] + rs[2] + rs[3];
        float Q = rq[0] + rq[1] + rq[2] + rq[3];
        const float inv = 1.0f / 65536.0f;
        float mean = S * inv;
        float var = Q * inv - mean * mean;
        float sc = gamma[o] * rsqrtf(var + 1e-5f);
        ss[o] = sc;
        ss[NC + o] = beta[o] - mean * sc;
    }
}

__global__ void k_apply(float* __restrict__ out, const float* __restrict__ x,
        const float* __restrict__ ss) {
    size_t i4 = (size_t)blockIdx.x * 256 + threadIdx.x;
    int o = (int)((i4 >> 10) & 255);
    float sc = ss[o], sh = ss[NC + o];
    float4 w = ((float4*)out)[i4];
    float4 xv = ((const float4*)x)[i4];
    float4 r;
    r.x = w.x * sc + sh + xv.x;
    r.y = w.y * sc + sh + xv.y;
    r.z = w.z * sc + sh + xv.z;
    r.w = w.w * sc + sh + xv.w;
    ((float4*)out)[i4] = r;
}

extern "C" void kernel_launch(void* const* d_in, const int* in_sizes, int n_in,
                              void* d_out, int out_size, void* d_ws, size_t ws_size,
                              hipStream_t stream) {
    const float* x       = (const float*)d_in[0];
    const float* y       = (const float*)d_in[1];
    const float* theta_w = (const float*)d_in[2];
    const float* theta_b = (const float*)d_in[3];
    const float* phi_w   = (const float*)d_in[4];
    const float* phi_b   = (const float*)d_in[5];
    const float* g_w     = (const float*)d_in[6];
    const float* g_b     = (const float*)d_in[7];
    const float* W_w     = (const float*)d_in[8];
    const float* W_b     = (const float*)d_in[9];
    const float* bn_g    = (const float*)d_in[10];
    const float* bn_b    = (const float*)d_in[11];
    float* ws  = (float*)d_ws;
    float* out = (float*)d_out;

    float*  wT0     = ws;                         // [256][128]
    float*  wT1     = ws + 32768;
    float*  wT2g    = ws + 65536;
    float*  wTW     = ws + 98304;                 // [128][256]
    ushort* thetaT  = (ushort*)(ws + 131072);     // bf16 [16][4096][128] = 4194304 floats
    float*  shared_f = ws + 4325376;              // 8388608 floats: phi_fullT(bf16) / g_full(f32) / z(f32)
    ushort* phiT    = (ushort*)(ws + 12713984);   // bf16 [16][1024][128]
    ushort* gbf     = (ushort*)(ws + 13762560);   // bf16 [16][128][1024]
    float*  part    = ws + 14811136;
    float*  partq   = ws + 15073280;
    float*  ss      = ws + 15335424;

    k_transpose<<<128, 256, 0, stream>>>(theta_w, wT0, CI, NC);
    k_transpose<<<128, 256, 0, stream>>>(phi_w,   wT1, CI, NC);
    k_transpose<<<128, 256, 0, stream>>>(g_w,     wT2g, CI, NC);
    k_transpose<<<128, 256, 0, stream>>>(W_w,     wTW, NC, CI);

    k_conv_t<<<NB * 64, 256, 0, stream>>>(x, wT0, theta_b, thetaT);
    k_conv_t<<<NB * 64, 256, 0, stream>>>(y, wT1, phi_b, (ushort*)shared_f);
    k_pool_t<<<NB * 4, 256, 0, stream>>>((ushort*)shared_f, phiT);
    k_conv<<<NB * 64, 256, 0, stream>>>(y, wT2g, g_b, shared_f);
    k_pool_bf<<<NB * CI, 256, 0, stream>>>(shared_f, gbf);

    k_attn_mfma<<<NB * 32, 256, 0, stream>>>(thetaT, phiT, gbf, shared_f);

    k_wz<<<NB * 64, 256, 0, stream>>>(shared_f, wTW, W_b, out, part, partq);
    k_bnstats<<<256, 256, 0, stream>>>(part, partq, bn_g, bn_b, ss);
    k_apply<<<16384, 256, 0, stream>>>(out, x, ss);
}

// Round 3
// 256.183 us; speedup vs baseline: 4.0816x; 1.9080x over previous
//
#include <hip/hip_runtime.h>
#include <cstdint>

#define HW 4096
#define NC 256
#define CI 128
#define NB 16
#define MP 1024

typedef __bf16 bfv8 __attribute__((ext_vector_type(8)));
typedef float f32x16 __attribute__((ext_vector_type(16)));

__device__ __forceinline__ uint32_t bfr(float x) {
    uint32_t u = __float_as_uint(x);
    return (u + 0x7fffu + ((u >> 16) & 1u)) >> 16;
}
__device__ __forceinline__ uint32_t pkbf(float a, float b) {
    return bfr(a) | (bfr(b) << 16);
}
__device__ __forceinline__ float b2f_lo(uint32_t u) { return __uint_as_float(u << 16); }
__device__ __forceinline__ float b2f_hi(uint32_t u) { return __uint_as_float(u & 0xffff0000u); }

// cast 4 weight tensors (each 32768 f32) to bf16
__global__ void k_castw(const float* __restrict__ a, const float* __restrict__ b,
                        const float* __restrict__ c, const float* __restrict__ d,
                        ushort* __restrict__ dst) {
    const float* srcs[4] = {a, b, c, d};
    const float* s = srcs[blockIdx.y];
    int i = (blockIdx.x * 256 + threadIdx.x) * 8;
    float4 v0 = *(const float4*)(s + i);
    float4 v1 = *(const float4*)(s + i + 4);
    uint4 o;
    o.x = pkbf(v0.x, v0.y); o.y = pkbf(v0.z, v0.w);
    o.z = pkbf(v1.x, v1.y); o.w = pkbf(v1.z, v1.w);
    *(uint4*)(dst + (size_t)blockIdx.y * 32768 + i) = o;
}

// MFMA 1x1 conv: in f32 [B][256][4096], wbf [O_TILE][256] bf16 -> outT [B][4096][O_TILE] bf16
template<int O_TILE, int NT>
__global__ __launch_bounds__(256) void k_conv_mfma(
        const float* __restrict__ in, const ushort* __restrict__ wbf,
        const float* __restrict__ bias0, const float* __restrict__ bias1,
        ushort* __restrict__ outT) {
    __shared__ ushort xs[NT * 256];
    const int t = threadIdx.x;
    constexpr int tilesPerB = 4096 / NT;
    const int b = blockIdx.x / tilesPerB;
    const int n0 = (blockIdx.x % tilesPerB) * NT;
    const float* inb = in + ((size_t)b * 256) * 4096 + n0;

    constexpr int RPP = 1024 / NT;
    const int c0 = t % RPP, q = t / RPP;
    #pragma unroll
    for (int p = 0; p < 256 / RPP; p++) {
        int c = c0 + p * RPP;
        float4 v = *(const float4*)(inb + (size_t)c * 4096 + q * 4);
        #pragma unroll
        for (int j = 0; j < 4; j++) {
            int n = q * 4 + j;
            xs[n * 256 + (c ^ ((n & 7) << 3))] = (ushort)bfr((&v.x)[j]);
        }
    }
    __syncthreads();

    const int lane = t & 63, w = t >> 6;
    const int ln = lane & 31, hi = lane >> 5;
    int ob0, nb0;
    if (O_TILE == 256) { ob0 = w * 2; nb0 = 0; }
    else               { ob0 = (w & 1) * 2; nb0 = (w >> 1) * 2; }

    f32x16 acc[2][2];
    #pragma unroll
    for (int i = 0; i < 2; i++)
        #pragma unroll
        for (int j = 0; j < 2; j++)
            #pragma unroll
            for (int k = 0; k < 16; k++) acc[i][j][k] = 0.f;

    const ushort* wr0 = wbf + (size_t)(ob0 * 32 + ln) * 256 + hi * 8;
    const ushort* wr1 = wr0 + 32 * 256;
    const int nr0 = nb0 * 32 + ln, nr1 = nr0 + 32;
    const int sw0 = (nr0 & 7) << 3, sw1 = (nr1 & 7) << 3;

    #pragma unroll 4
    for (int ks = 0; ks < 16; ks++) {
        int k = ks * 16 + hi * 8;
        bfv8 wf0 = *(const bfv8*)(wr0 + ks * 16);
        bfv8 wf1 = *(const bfv8*)(wr1 + ks * 16);
        bfv8 x0 = *(const bfv8*)&xs[nr0 * 256 + (k ^ sw0)];
        bfv8 x1 = *(const bfv8*)&xs[nr1 * 256 + (k ^ sw1)];
        acc[0][0] = __builtin_amdgcn_mfma_f32_32x32x16_bf16(wf0, x0, acc[0][0], 0, 0, 0);
        acc[0][1] = __builtin_amdgcn_mfma_f32_32x32x16_bf16(wf0, x1, acc[0][1], 0, 0, 0);
        acc[1][0] = __builtin_amdgcn_mfma_f32_32x32x16_bf16(wf1, x0, acc[1][0], 0, 0, 0);
        acc[1][1] = __builtin_amdgcn_mfma_f32_32x32x16_bf16(wf1, x1, acc[1][1], 0, 0, 0);
    }

    #pragma unroll
    for (int oi = 0; oi < 2; oi++) {
        int obb = (ob0 + oi) * 32;
        #pragma unroll
        for (int grp = 0; grp < 4; grp++) {
            int og = obb + grp * 8 + hi * 4;
            const float* bp = (O_TILE == 256 && og >= 128) ? bias1 : bias0;
            float4 bv = *(const float4*)&bp[og & 127];
            #pragma unroll
            for (int ni = 0; ni < 2; ni++) {
                int n = n0 + (nb0 + ni) * 32 + ln;
                float r0 = acc[oi][ni][grp * 4 + 0] + bv.x;
                float r1 = acc[oi][ni][grp * 4 + 1] + bv.y;
                float r2 = acc[oi][ni][grp * 4 + 2] + bv.z;
                float r3 = acc[oi][ni][grp * 4 + 3] + bv.w;
                uint2 pk;
                pk.x = pkbf(r0, r1); pk.y = pkbf(r2, r3);
                *(uint2*)&outT[((size_t)b * 4096 + n) * O_TILE + og] = pk;
            }
        }
    }
}

// pool phig [B][4096][256] -> phiT [B][1024][128] and g [B][128][1024]
__global__ __launch_bounds__(256) void k_pool(const ushort* __restrict__ phig,
        ushort* __restrict__ phiT, ushort* __restrict__ gout) {
    __shared__ ushort gt[128][33];
    int b = blockIdx.x >> 5, ph = blockIdx.x & 31;
    int t = threadIdx.x;
    int c8 = (t & 31) * 8, pg = t >> 5;
    const ushort* base = phig + ((size_t)b * 4096) * 256;
    #pragma unroll
    for (int i = 0; i < 4; i++) {
        int pw = pg * 4 + i;
        int m = ph * 32 + pw;
        int n00 = 128 * ph + 2 * pw;
        uint4 a = *(const uint4*)(base + (size_t)(n00) * 256 + c8);
        uint4 bb = *(const uint4*)(base + (size_t)(n00 + 1) * 256 + c8);
        uint4 cc = *(const uint4*)(base + (size_t)(n00 + 64) * 256 + c8);
        uint4 dd = *(const uint4*)(base + (size_t)(n00 + 65) * 256 + c8);
        uint4 o;
        const uint32_t* pa = &a.x; const uint32_t* pbp = &bb.x;
        const uint32_t* pc = &cc.x; const uint32_t* pd = &dd.x;
        uint32_t* po = &o.x;
        #pragma unroll
        for (int k = 0; k < 4; k++) {
            float lo = fmaxf(fmaxf(b2f_lo(pa[k]), b2f_lo(pbp[k])), fmaxf(b2f_lo(pc[k]), b2f_lo(pd[k])));
            float hi = fmaxf(fmaxf(b2f_hi(pa[k]), b2f_hi(pbp[k])), fmaxf(b2f_hi(pc[k]), b2f_hi(pd[k])));
            po[k] = (__float_as_uint(lo) >> 16) | (__float_as_uint(hi) & 0xffff0000u);
        }
        if (c8 < 128) {
            *(uint4*)&phiT[((size_t)b * MP + m) * CI + c8] = o;
        } else {
            int c = c8 - 128;
            #pragma unroll
            for (int j = 0; j < 8; j++) {
                uint32_t word = po[j >> 1];
                gt[c + j][pw] = (j & 1) ? (ushort)(word >> 16) : (ushort)(word & 0xffffu);
            }
        }
    }
    __syncthreads();
    {
        int c = t >> 1, half = t & 1;
        ushort* grow = gout + ((size_t)b * CI + c) * MP + ph * 32 + half * 16;
        uint32_t wv[8];
        #pragma unroll
        for (int k = 0; k < 8; k++) {
            wv[k] = (uint32_t)gt[c][half * 16 + 2 * k] | ((uint32_t)gt[c][half * 16 + 2 * k + 1] << 16);
        }
        *(uint4*)grow = make_uint4(wv[0], wv[1], wv[2], wv[3]);
        *(uint4*)(grow + 8) = make_uint4(wv[4], wv[5], wv[6], wv[7]);
    }
}

// flash attention -> z bf16 [B][4096][128]
__global__ __launch_bounds__(256) void k_attn_mfma(
        const ushort* __restrict__ thetaT, const ushort* __restrict__ phiT,
        const ushort* __restrict__ gmat, ushort* __restrict__ zout) {
    int t = threadIdx.x;
    int wave = t >> 6, lane = t & 63;
    int nq = lane & 31, hi = lane >> 5;
    int b = blockIdx.x >> 5;
    int nblk = blockIdx.x & 31;
    int n0 = (nblk << 7) + (wave << 5);

    bfv8 qf[8];
    {
        const ushort* tb = thetaT + ((size_t)b * HW + n0 + nq) * CI + hi * 8;
        #pragma unroll
        for (int s = 0; s < 8; s++) qf[s] = *(const bfv8*)(tb + s * 16);
    }
    f32x16 zacc[4];
    #pragma unroll
    for (int ct = 0; ct < 4; ct++)
        #pragma unroll
        for (int i = 0; i < 16; i++) zacc[ct][i] = 0.f;
    float run_max = -1e30f, run_sum = 0.f;

    const ushort* pb = phiT + ((size_t)b * MP + nq) * CI + hi * 8;
    const ushort* gb = gmat + ((size_t)b * CI + nq) * MP + hi * 8;

    for (int m0 = 0; m0 < MP; m0 += 64) {
        f32x16 sA, sB;
        #pragma unroll
        for (int i = 0; i < 16; i++) { sA[i] = 0.f; sB[i] = 0.f; }
        const ushort* paA = pb + (size_t)m0 * CI;
        const ushort* paB = paA + 32 * CI;
        __builtin_amdgcn_s_setprio(1);
        #pragma unroll
        for (int ks = 0; ks < 8; ks++) {
            sA = __builtin_amdgcn_mfma_f32_32x32x16_bf16(*(const bfv8*)(paA + ks * 16), qf[ks], sA, 0, 0, 0);
            sB = __builtin_amdgcn_mfma_f32_32x32x16_bf16(*(const bfv8*)(paB + ks * 16), qf[ks], sB, 0, 0, 0);
        }
        __builtin_amdgcn_s_setprio(0);
        float mx = sA[0];
        #pragma unroll
        for (int i = 1; i < 16; i++) mx = fmaxf(mx, sA[i]);
        #pragma unroll
        for (int i = 0; i < 16; i++) mx = fmaxf(mx, sB[i]);
        float gmx = fmaxf(mx, __shfl_xor(mx, 32, 64));
        if (!__all(gmx - run_max <= 8.0f)) {
            float nm = fmaxf(run_max, gmx);
            float sc = __expf(run_max - nm);
            run_sum *= sc;
            #pragma unroll
            for (int ct = 0; ct < 4; ct++)
                #pragma unroll
                for (int i = 0; i < 16; i++) zacc[ct][i] *= sc;
            run_max = nm;
        }
        float pA[16], pB[16];
        #pragma unroll
        for (int i = 0; i < 16; i++) { pA[i] = __expf(sA[i] - run_max); run_sum += pA[i]; }
        #pragma unroll
        for (int i = 0; i < 16; i++) { pB[i] = __expf(sB[i] - run_max); run_sum += pB[i]; }

        uint32_t wA[8], wB[8], tA[8], tB[8];
        #pragma unroll
        for (int j = 0; j < 8; j++) { wA[j] = pkbf(pA[2 * j], pA[2 * j + 1]); wB[j] = pkbf(pB[2 * j], pB[2 * j + 1]); }
        #pragma unroll
        for (int j = 0; j < 8; j++) { tA[j] = (uint32_t)__shfl_xor((int)wA[j], 32, 64); tB[j] = (uint32_t)__shfl_xor((int)wB[j], 32, 64); }
        bool lo = (hi == 0);
        union PU { uint32_t u[4]; bfv8 v; } p0A, p1A, p0B, p1B;
        p0A.u[0] = lo ? wA[0] : tA[2]; p0A.u[1] = lo ? wA[1] : tA[3];
        p0A.u[2] = lo ? tA[0] : wA[2]; p0A.u[3] = lo ? tA[1] : wA[3];
        p1A.u[0] = lo ? wA[4] : tA[6]; p1A.u[1] = lo ? wA[5] : tA[7];
        p1A.u[2] = lo ? tA[4] : wA[6]; p1A.u[3] = lo ? tA[5] : wA[7];
        p0B.u[0] = lo ? wB[0] : tB[2]; p0B.u[1] = lo ? wB[1] : tB[3];
        p0B.u[2] = lo ? tB[0] : wB[2]; p0B.u[3] = lo ? tB[1] : wB[3];
        p1B.u[0] = lo ? wB[4] : tB[6]; p1B.u[1] = lo ? wB[5] : tB[7];
        p1B.u[2] = lo ? tB[4] : wB[6]; p1B.u[3] = lo ? tB[5] : wB[7];

        const ushort* ga0 = gb + m0;
        __builtin_amdgcn_s_setprio(1);
        #pragma unroll
        for (int ct = 0; ct < 4; ct++) {
            const ushort* ga = ga0 + (size_t)(ct * 32) * MP;
            zacc[ct] = __builtin_amdgcn_mfma_f32_32x32x16_bf16(*(const bfv8*)(ga), p0A.v, zacc[ct], 0, 0, 0);
            zacc[ct] = __builtin_amdgcn_mfma_f32_32x32x16_bf16(*(const bfv8*)(ga + 16), p1A.v, zacc[ct], 0, 0, 0);
            zacc[ct] = __builtin_amdgcn_mfma_f32_32x32x16_bf16(*(const bfv8*)(ga + 32), p0B.v, zacc[ct], 0, 0, 0);
            zacc[ct] = __builtin_amdgcn_mfma_f32_32x32x16_bf16(*(const bfv8*)(ga + 48), p1B.v, zacc[ct], 0, 0, 0);
        }
        __builtin_amdgcn_s_setprio(0);
    }
    float tot = run_sum + __shfl_xor(run_sum, 32, 64);
    float rinv = 1.f / tot;
    ushort* zr = zout + ((size_t)b * HW + n0 + nq) * CI;
    #pragma unroll
    for (int ct = 0; ct < 4; ct++) {
        #pragma unroll
        for (int grp = 0; grp < 4; grp++) {
            int c0 = ct * 32 + grp * 8 + hi * 4;
            uint2 pk;
            pk.x = pkbf(zacc[ct][grp * 4 + 0] * rinv, zacc[ct][grp * 4 + 1] * rinv);
            pk.y = pkbf(zacc[ct][grp * 4 + 2] * rinv, zacc[ct][grp * 4 + 3] * rinv);
            *(uint2*)(zr + c0) = pk;
        }
    }
}

// wz GEMM: z bf16 [B][4096][128], Wbf [256][128] bf16 -> out f32 [B][256][4096] + BN partials
__global__ __launch_bounds__(256) void k_wz_mfma(
        const ushort* __restrict__ z, const ushort* __restrict__ Wbf,
        const float* __restrict__ Wb, float* __restrict__ out,
        float* __restrict__ part) {
    __shared__ ushort zs[128 * 128];
    int t = threadIdx.x;
    int mtile = blockIdx.x;
    int oh = blockIdx.y;
    int b = mtile >> 5;
    int n0 = (mtile & 31) << 7;
    const ushort* zt = z + ((size_t)b * 4096 + n0) * 128;
    #pragma unroll
    for (int it = 0; it < 8; it++) {
        int d = (it * 256 + t) * 16;
        uint4 v = *(const uint4*)((const char*)zt + d);
        int n = d >> 8;
        int widx = (n << 7) + (((d & 255) ^ ((n & 7) << 4)) >> 1);
        *(uint4*)&zs[widx] = v;
    }
    __syncthreads();
    int lane = t & 63, w = t >> 6;
    int ln = lane & 31, hi = lane >> 5;
    int wr = w >> 1, wc = w & 1;
    f32x16 acc[2][2];
    #pragma unroll
    for (int i = 0; i < 2; i++)
        #pragma unroll
        for (int j = 0; j < 2; j++)
            #pragma unroll
            for (int k = 0; k < 16; k++) acc[i][j][k] = 0.f;
    const ushort* w0 = Wbf + (size_t)(oh * 128 + wc * 64 + ln) * 128 + hi * 8;
    const ushort* w1 = w0 + 32 * 128;
    int nr0 = wr * 64 + ln, nr1 = nr0 + 32;
    int sw0 = (nr0 & 7) << 3, sw1 = (nr1 & 7) << 3;
    #pragma unroll
    for (int ks = 0; ks < 8; ks++) {
        int k = ks * 16 + hi * 8;
        bfv8 a0 = *(const bfv8*)&zs[(nr0 << 7) + (k ^ sw0)];
        bfv8 a1 = *(const bfv8*)&zs[(nr1 << 7) + (k ^ sw1)];
        bfv8 b0 = *(const bfv8*)(w0 + ks * 16);
        bfv8 b1 = *(const bfv8*)(w1 + ks * 16);
        acc[0][0] = __builtin_amdgcn_mfma_f32_32x32x16_bf16(a0, b0, acc[0][0], 0, 0, 0);
        acc[0][1] = __builtin_amdgcn_mfma_f32_32x32x16_bf16(a0, b1, acc[0][1], 0, 0, 0);
        acc[1][0] = __builtin_amdgcn_mfma_f32_32x32x16_bf16(a1, b0, acc[1][0], 0, 0, 0);
        acc[1][1] = __builtin_amdgcn_mfma_f32_32x32x16_bf16(a1, b1, acc[1][1], 0, 0, 0);
    }
    #pragma unroll
    for (int obi = 0; obi < 2; obi++) {
        int o = oh * 128 + wc * 64 + obi * 32 + ln;
        float bv = Wb[o];
        float* orow = out + ((size_t)b * 256 + o) * 4096 + n0;
        float s = 0.f, qq = 0.f;
        #pragma unroll
        for (int nbi = 0; nbi < 2; nbi++) {
            #pragma unroll
            for (int grp = 0; grp < 4; grp++) {
                float4 vv;
                #pragma unroll
                for (int j = 0; j < 4; j++) {
                    float v = acc[nbi][obi][grp * 4 + j] + bv;
                    (&vv.x)[j] = v;
                    s += v; qq += v * v;
                }
                int n = (wr * 2 + nbi) * 32 + grp * 8 + hi * 4;
                *(float4*)(orow + n) = vv;
            }
        }
        s += __shfl_xor(s, 32, 64);
        qq += __shfl_xor(qq, 32, 64);
        if (hi == 0) {
            float* pr = part + (size_t)(mtile * 2 + wr) * 512;
            pr[o] = s;
            pr[256 + o] = qq;
        }
    }
}

__global__ __launch_bounds__(256) void k_bnstats(const float* __restrict__ part,
        const float* __restrict__ gamma, const float* __restrict__ beta,
        float* __restrict__ ss) {
    int o = blockIdx.x, t = threadIdx.x;
    float s = 0.f, q = 0.f;
    for (int k = t; k < 1024; k += 256) {
        s += part[(size_t)k * 512 + o];
        q += part[(size_t)k * 512 + 256 + o];
    }
    #pragma unroll
    for (int d = 32; d > 0; d >>= 1) { s += __shfl_down(s, d, 64); q += __shfl_down(q, d, 64); }
    __shared__ float rs[4], rq[4];
    int wave = t >> 6, lane = t & 63;
    if (lane == 0) { rs[wave] = s; rq[wave] = q; }
    __syncthreads();
    if (t == 0) {
        float S = rs[0] + rs[1] + rs[2] + rs[3];
        float Q = rq[0] + rq[1] + rq[2] + rq[3];
        const float inv = 1.0f / 65536.0f;
        float mean = S * inv;
        float var = Q * inv - mean * mean;
        float sc = gamma[o] * rsqrtf(var + 1e-5f);
        ss[o] = sc;
        ss[NC + o] = beta[o] - mean * sc;
    }
}

__global__ void k_apply(float* __restrict__ out, const float* __restrict__ x,
        const float* __restrict__ ss) {
    size_t i4 = (size_t)blockIdx.x * 256 + threadIdx.x;
    int o = (int)((i4 >> 10) & 255);
    float sc = ss[o], sh = ss[NC + o];
    float4 w = ((float4*)out)[i4];
    float4 xv = ((const float4*)x)[i4];
    float4 r;
    r.x = w.x * sc + sh + xv.x;
    r.y = w.y * sc + sh + xv.y;
    r.z = w.z * sc + sh + xv.z;
    r.w = w.w * sc + sh + xv.w;
    ((float4*)out)[i4] = r;
}

extern "C" void kernel_launch(void* const* d_in, const int* in_sizes, int n_in,
                              void* d_out, int out_size, void* d_ws, size_t ws_size,
                              hipStream_t stream) {
    const float* x       = (const float*)d_in[0];
    const float* y       = (const float*)d_in[1];
    const float* theta_w = (const float*)d_in[2];
    const float* theta_b = (const float*)d_in[3];
    const float* phi_w   = (const float*)d_in[4];
    const float* phi_b   = (const float*)d_in[5];
    const float* g_w     = (const float*)d_in[6];
    const float* g_b     = (const float*)d_in[7];
    const float* W_w     = (const float*)d_in[8];
    const float* W_b     = (const float*)d_in[9];
    const float* bn_g    = (const float*)d_in[10];
    const float* bn_b    = (const float*)d_in[11];
    float* ws  = (float*)d_ws;
    float* out = (float*)d_out;

    ushort* wbf    = (ushort*)ws;
    ushort* thetaT = (ushort*)(ws + 65536);
    ushort* phig   = (ushort*)(ws + 4259840);
    ushort* zbuf   = phig;
    ushort* phiT   = (ushort*)(ws + 12648448);
    ushort* gbuf   = (ushort*)(ws + 13697024);
    float*  part   = ws + 14745600;
    float*  ss     = ws + 15269888;

    k_castw<<<dim3(16, 4), 256, 0, stream>>>(theta_w, phi_w, g_w, W_w, wbf);

    k_conv_mfma<128, 128><<<NB * 32, 256, 0, stream>>>(x, wbf, theta_b, theta_b, thetaT);
    k_conv_mfma<256, 64><<<NB * 64, 256, 0, stream>>>(y, wbf + 32768, phi_b, g_b, phig);

    k_pool<<<NB * 32, 256, 0, stream>>>(phig, phiT, gbuf);

    k_attn_mfma<<<NB * 32, 256, 0, stream>>>(thetaT, phiT, gbuf, zbuf);

    k_wz_mfma<<<dim3(NB * 32, 2), 256, 0, stream>>>(zbuf, wbf + 98304, W_b, out, part);
    k_bnstats<<<256, 256, 0, stream>>>(part, bn_g, bn_b, ss);
    k_apply<<<16384, 256, 0, stream>>>(out, x, ss);
}